// Round 8
// baseline (195.014 us; speedup 1.0000x reference)
//
#include <hip/hip_runtime.h>
#include <math.h>

#define Hh 128
#define Ww 128
#define Dd 256
#define Bb 4
#define HW (Hh*Ww)        // 16384
#define NPIX (Bb*HW)      // 65536
#define WP 132            // padded width/height (2-px zero ring)

typedef __attribute__((ext_vector_type(8))) short s16x8;   // 8 bf16 (4 VGPRs)
typedef __attribute__((ext_vector_type(4))) float f32x4;

__device__ __forceinline__ unsigned short f2bf(float f) {
    unsigned u = __float_as_uint(f);
    u += 0x7FFF + ((u >> 16) & 1);
    return (unsigned short)(u >> 16);
}

__device__ __forceinline__ float gelu_exact(float v) {
    return 0.5f * v * (1.0f + erff(v * 0.70710678118654752f));
}

// ring pixel i in [0,1040) -> (y,x) on the 2-px border of a 132x132 image
__device__ __forceinline__ void ring_yx(int i, int& y, int& x) {
    if (i < 264) { y = i / 132; x = i - y * 132; }
    else if (i < 528) { int j = i - 264; int r = j / 132; y = 130 + r; x = j - r * 132; }
    else { int j = i - 528; y = 2 + (j >> 2); int m = j & 3; x = (m < 2) ? m : 128 + m; }
}

// ---------- K0: merged ring-zero + weight transpose + normalize ----------
// kn/qn use a PERMUTED channel layout: lane l (of 32) owns ch {l*4..l*4+3, 128+l*4..+3}
// stored contiguously at short offset l*8. Same permutation for kn and qn -> corr's
// dot products are invariant. Gives 16-B stores instead of 8-B.
// blocks 0..609    : ring zeros + weight transpose
// blocks 610..4705 : vis -> kn (32-lane groups, 2 px each)
// blocks 4706..5729: rubin bilinear -> qn (LDS-staged 6x6 tokens, 32-lane groups, 8 px)
__global__ __launch_bounds__(256) void setup_norm(const float* __restrict__ w0,
                                                  const float* __restrict__ w1,
                                                  const float* __restrict__ w2,
                                                  unsigned short* __restrict__ wb0,
                                                  unsigned short* __restrict__ wb1,
                                                  unsigned short* __restrict__ wb2,
                                                  unsigned short* __restrict__ xbp,
                                                  unsigned short* __restrict__ h1p,
                                                  unsigned short* __restrict__ h2p,
                                                  const float* __restrict__ vis,
                                                  const float* __restrict__ rub,
                                                  unsigned short* __restrict__ kn,
                                                  unsigned short* __restrict__ qn) {
    __shared__ float stok[36 * 260];
    int tid = threadIdx.x;
    int blk = blockIdx.x;
    if (blk < 610) {
        int t = blk * 256 + tid;
        if (t < 66560) {
            uint4 z = (uint4){0, 0, 0, 0};
            if (t < 33280) {
                int img = t / 8320; int r = t - img * 8320; int px = r >> 3, g = r & 7;
                int y, x; ring_yx(px, y, x);
                *(uint4*)(xbp + ((size_t)(img * WP + y) * WP + x) * 64 + g * 8) = z;
            } else {
                int u = t - 33280;
                unsigned short* base = (u < 16640) ? h1p : h2p;
                int v = (u < 16640) ? u : u - 16640;
                int img = v / 4160; int r = v - img * 4160; int px = r >> 2, g = r & 3;
                int y, x; ring_yx(px, y, x);
                *(uint4*)(base + ((size_t)(img * WP + y) * WP + x) * 32 + g * 8) = z;
            }
            return;
        }
        int u = t - 66560;
        if (u < 51200) {
            int tap = u >> 11; int r = u & 2047; int n = r >> 6; int k = r & 63;
            wb0[u] = (k < 52) ? f2bf(w0[n * 1300 + k * 25 + tap]) : (unsigned short)0;
        } else if (u < 76800) {
            int v = u - 51200; int tap = v >> 10; int r = v & 1023; int n = r >> 5; int k = r & 31;
            wb1[v] = f2bf(w1[n * 800 + k * 25 + tap]);
        } else if (u < 89600) {
            int v = u - 76800; int tap = v >> 9; int r = v & 511; int n = r >> 5; int k = r & 31;
            wb2[v] = (n < 2) ? f2bf(w2[n * 800 + k * 25 + tap]) : (unsigned short)0;
        }
        return;
    }
    int nb = blk - 610;
    int g32 = tid >> 5, l = tid & 31;
    if (nb < 4096) {
        // vis: 8 groups x 2 px = 16 px per block
        int pix0 = nb * 16 + g32 * 2;
        const float* base0 = vis + (size_t)pix0 * Dd + l * 4;
        float4 a0 = *(const float4*)(base0);
        float4 b0 = *(const float4*)(base0 + 128);
        float4 a1 = *(const float4*)(base0 + 256);
        float4 b1 = *(const float4*)(base0 + 384);
        float ss0 = a0.x * a0.x + a0.y * a0.y + a0.z * a0.z + a0.w * a0.w +
                    b0.x * b0.x + b0.y * b0.y + b0.z * b0.z + b0.w * b0.w;
        float ss1 = a1.x * a1.x + a1.y * a1.y + a1.z * a1.z + a1.w * a1.w +
                    b1.x * b1.x + b1.y * b1.y + b1.z * b1.z + b1.w * b1.w;
#pragma unroll
        for (int o = 1; o <= 16; o <<= 1) {
            ss0 += __shfl_xor(ss0, o, 64);
            ss1 += __shfl_xor(ss1, o, 64);
        }
        float inv0 = __builtin_amdgcn_rsqf(fmaxf(ss0, 1e-24f));
        float inv1 = __builtin_amdgcn_rsqf(fmaxf(ss1, 1e-24f));
        uint4 o0, o1;
        o0.x = f2bf(a0.x * inv0) | ((unsigned)f2bf(a0.y * inv0) << 16);
        o0.y = f2bf(a0.z * inv0) | ((unsigned)f2bf(a0.w * inv0) << 16);
        o0.z = f2bf(b0.x * inv0) | ((unsigned)f2bf(b0.y * inv0) << 16);
        o0.w = f2bf(b0.z * inv0) | ((unsigned)f2bf(b0.w * inv0) << 16);
        o1.x = f2bf(a1.x * inv1) | ((unsigned)f2bf(a1.y * inv1) << 16);
        o1.y = f2bf(a1.z * inv1) | ((unsigned)f2bf(a1.w * inv1) << 16);
        o1.z = f2bf(b1.x * inv1) | ((unsigned)f2bf(b1.y * inv1) << 16);
        o1.w = f2bf(b1.z * inv1) | ((unsigned)f2bf(b1.w * inv1) << 16);
        *(uint4*)(kn + (size_t)pix0 * Dd + l * 8) = o0;
        *(uint4*)(kn + (size_t)(pix0 + 1) * Dd + l * 8) = o1;
    } else {
        int blk2 = nb - 4096;                // 1024 tiles of 8x8 output px
        int b = blk2 >> 8;
        int rem = blk2 & 255;
        int ty = rem >> 4, tx = rem & 15;
        int oy0 = ty * 8, ox0 = tx * 8;
        int rb = ty * 4 - 1, cb = tx * 4 - 1;    // token window base (6x6)
#pragma unroll
        for (int i = 0; i < 9; i++) {
            int g = i * 256 + tid;               // 2304 granules exactly
            int t = g >> 6, c = g & 63;
            int jy = t / 6, jx = t - jy * 6;
            int gy = min(max(rb + jy, 0), 63);
            int gx = min(max(cb + jx, 0), 63);
            *(float4*)&stok[t * 260 + c * 4] =
                *(const float4*)(rub + ((size_t)(b * 4096 + gy * 64 + gx)) * 256 + c * 4);
        }
        __syncthreads();
        // 8 groups x 8 px
        for (int k = 0; k < 8; k++) {
            int pp = g32 * 8 + k;
            int r = pp >> 3, c2 = pp & 7;
            int yo = oy0 + r, xo = ox0 + c2;
            float sy = 0.5f * yo - 0.25f, sx = 0.5f * xo - 0.25f;
            float fyf = floorf(sy), fxf = floorf(sx);
            float fy = sy - fyf, fx = sx - fxf;
            int jy0 = (int)fyf - rb, jx0 = (int)fxf - cb;   // in [0,4]
            const float* t00 = &stok[(jy0 * 6 + jx0) * 260];
            const float* t01 = t00 + 260;
            const float* t10 = t00 + 6 * 260;
            const float* t11 = t10 + 260;
            float w00 = (1.f - fy) * (1.f - fx), w01 = (1.f - fy) * fx;
            float w10 = fy * (1.f - fx), w11 = fy * fx;
            float4 av, bv;
            {
                float4 A0 = *(const float4*)(t00 + l * 4);
                float4 B0 = *(const float4*)(t01 + l * 4);
                float4 C0 = *(const float4*)(t10 + l * 4);
                float4 D0 = *(const float4*)(t11 + l * 4);
                av.x = w00 * A0.x + w01 * B0.x + w10 * C0.x + w11 * D0.x;
                av.y = w00 * A0.y + w01 * B0.y + w10 * C0.y + w11 * D0.y;
                av.z = w00 * A0.z + w01 * B0.z + w10 * C0.z + w11 * D0.z;
                av.w = w00 * A0.w + w01 * B0.w + w10 * C0.w + w11 * D0.w;
                float4 A1 = *(const float4*)(t00 + 128 + l * 4);
                float4 B1 = *(const float4*)(t01 + 128 + l * 4);
                float4 C1 = *(const float4*)(t10 + 128 + l * 4);
                float4 D1 = *(const float4*)(t11 + 128 + l * 4);
                bv.x = w00 * A1.x + w01 * B1.x + w10 * C1.x + w11 * D1.x;
                bv.y = w00 * A1.y + w01 * B1.y + w10 * C1.y + w11 * D1.y;
                bv.z = w00 * A1.z + w01 * B1.z + w10 * C1.z + w11 * D1.z;
                bv.w = w00 * A1.w + w01 * B1.w + w10 * C1.w + w11 * D1.w;
            }
            float ss = av.x * av.x + av.y * av.y + av.z * av.z + av.w * av.w +
                       bv.x * bv.x + bv.y * bv.y + bv.z * bv.z + bv.w * bv.w;
#pragma unroll
            for (int o = 1; o <= 16; o <<= 1) ss += __shfl_xor(ss, o, 64);
            float inv = __builtin_amdgcn_rsqf(fmaxf(ss, 1e-24f));
            size_t pix = (size_t)(b << 14) + yo * 128 + xo;
            uint4 o4;
            o4.x = f2bf(av.x * inv) | ((unsigned)f2bf(av.y * inv) << 16);
            o4.y = f2bf(av.z * inv) | ((unsigned)f2bf(av.w * inv) << 16);
            o4.z = f2bf(bv.x * inv) | ((unsigned)f2bf(bv.y * inv) << 16);
            o4.w = f2bf(bv.z * inv) | ((unsigned)f2bf(bv.w * inv) << 16);
            *(uint4*)(qn + pix * Dd + l * 8) = o4;
        }
    }
}

// ---------- K2: corr, 64-ch chunks (4 iters, 10 syncs), LDS union halo/sC ----------
__global__ __launch_bounds__(512, 4) void corr_block(const unsigned short* __restrict__ qn,
                                                     const unsigned short* __restrict__ kn,
                                                     const float* __restrict__ log_temp,
                                                     unsigned short* __restrict__ xb,
                                                     float* __restrict__ out) {
    // halo: 320 px (308 used) x 144 B (64ch bf16 + 16B pad) = 46080 B
    // sC (output transpose tile, 128 px x 65 u32 = 33280 B) ALIASES the halo
    // region -- halo is dead after the K-loop.
    __shared__ __align__(16) char smem[320 * 144];
    unsigned* sC = (unsigned*)smem;
    int tid = threadIdx.x;
    int wid = tid >> 6, lane = tid & 63, l15 = lane & 15, quad = lane >> 4;
    int blk = blockIdx.x;                    // 512 = 4 b x 16 ty x 8 tx
    int b = blk >> 7, rem = blk & 127;
    int y0 = (rem >> 3) << 3, x0 = (rem & 7) << 4;
    int y = y0 + wid;

    // staging descriptors: 2560 granules (5 rounds x 512), granule = 16 B
    int soff[5], dstf[5];
#pragma unroll
    for (int i = 0; i < 5; i++) {
        int g = i * 512 + tid;
        int px = g >> 3, sub = g & 7;
        int pxc = min(px, 307);
        int ry = pxc / 22, rx = pxc - ry * 22;
        int yy = min(max(y0 - 3 + ry, 0), 127);
        int xx = min(max(x0 - 3 + rx, 0), 127);
        soff[i] = ((b << 14) + yy * 128 + xx) * 256 + sub * 8;   // shorts
        dstf[i] = px * 144 + sub * 16;                            // bytes
    }
    int lpixoff[10];
#pragma unroll
    for (int f = 0; f < 10; f++) {
        int p = min(f * 16 + l15, 153);
        int pr = p / 22, pc = p - pr * 22;
        lpixoff[f] = ((wid + pr) * 22 + pc) * 144 + quad * 16;
    }
    int aoff = ((b << 14) + y * 128 + x0 + l15) * 256 + quad * 8;   // shorts

    f32x4 acc[10];
#pragma unroll
    for (int f = 0; f < 10; f++) acc[f] = (f32x4){0.f, 0.f, 0.f, 0.f};

    uint4 st0 = *(const uint4*)(kn + soff[0]);
    uint4 st1 = *(const uint4*)(kn + soff[1]);
    uint4 st2 = *(const uint4*)(kn + soff[2]);
    uint4 st3 = *(const uint4*)(kn + soff[3]);
    uint4 st4 = *(const uint4*)(kn + soff[4]);
    s16x8 a0 = *(const s16x8*)(qn + aoff);
    s16x8 a1 = *(const s16x8*)(qn + aoff + 32);
    for (int c4 = 0; c4 < 4; c4++) {
        uint4 w0 = st0, w1 = st1, w2 = st2, w3 = st3, w4 = st4;
        s16x8 wa0 = a0, wa1 = a1;
        if (c4 < 3) {
            int co = (c4 + 1) * 64;
            st0 = *(const uint4*)(kn + soff[0] + co);
            st1 = *(const uint4*)(kn + soff[1] + co);
            st2 = *(const uint4*)(kn + soff[2] + co);
            st3 = *(const uint4*)(kn + soff[3] + co);
            st4 = *(const uint4*)(kn + soff[4] + co);
            a0 = *(const s16x8*)(qn + aoff + co);
            a1 = *(const s16x8*)(qn + aoff + co + 32);
        }
        __syncthreads();
        *(uint4*)(smem + dstf[0]) = w0;
        *(uint4*)(smem + dstf[1]) = w1;
        *(uint4*)(smem + dstf[2]) = w2;
        *(uint4*)(smem + dstf[3]) = w3;
        *(uint4*)(smem + dstf[4]) = w4;
        __syncthreads();
#pragma unroll
        for (int f = 0; f < 10; f++) {
            s16x8 bf = *(const s16x8*)(smem + lpixoff[f]);
            acc[f] = __builtin_amdgcn_mfma_f32_16x16x32_bf16(wa0, bf, acc[f], 0, 0, 0);
        }
#pragma unroll
        for (int f = 0; f < 10; f++) {
            s16x8 bf = *(const s16x8*)(smem + lpixoff[f] + 64);
            acc[f] = __builtin_amdgcn_mfma_f32_16x16x32_bf16(wa1, bf, acc[f], 0, 0, 0);
        }
    }
    __syncthreads();   // halo dead; smem becomes sC

    // zero pad-channels 52..63 of the transpose tile
#pragma unroll
    for (int i = 0; i < 3; i++) {
        int g = i * 512 + tid;               // 1536 exactly
        int px = g / 12, ch = 52 + g - (g / 12) * 12;
        sC[px * 65 + ch] = 0u;
    }

    float inv_temp = expf(-log_temp[0]);
    float vmax[4] = {-1e30f, -1e30f, -1e30f, -1e30f};
#pragma unroll
    for (int f = 0; f < 10; f++) {
        int n = f * 16 + l15;
        if (n <= 153) {
            int dy = n / 22 - 3;
            int rx = n - (dy + 3) * 22;
#pragma unroll
            for (int i = 0; i < 4; i++) {
                int m = quad * 4 + i;
                int dx = rx - m - 3;
                if ((unsigned)(dx + 3) <= 6u) vmax[i] = fmaxf(vmax[i], acc[f][i]);
            }
        }
    }
#pragma unroll
    for (int o = 1; o <= 8; o <<= 1) {
#pragma unroll
        for (int i = 0; i < 4; i++) vmax[i] = fmaxf(vmax[i], __shfl_xor(vmax[i], o, 64));
    }
    float se[4] = {0, 0, 0, 0}, sey[4] = {0, 0, 0, 0}, sex[4] = {0, 0, 0, 0}, emax[4] = {0, 0, 0, 0};
#pragma unroll
    for (int f = 0; f < 10; f++) {
        int n = f * 16 + l15;
        if (n <= 153) {
            int dy = n / 22 - 3;
            int rx = n - (dy + 3) * 22;
#pragma unroll
            for (int i = 0; i < 4; i++) {
                int m = quad * 4 + i;
                int dx = rx - m - 3;
                if ((unsigned)(dx + 3) <= 6u) {
                    float v = acc[f][i];
                    float e = expf((v - vmax[i]) * inv_temp);
                    se[i] += e;
                    sey[i] += e * (float)dy;
                    sex[i] += e * (float)dx;
                    emax[i] = fmaxf(emax[i], e);
                    sC[(wid * 16 + m) * 65 + 2 + (dy + 3) * 7 + (dx + 3)] = (unsigned)f2bf(v);
                }
            }
        }
    }
#pragma unroll
    for (int o = 1; o <= 8; o <<= 1) {
#pragma unroll
        for (int i = 0; i < 4; i++) {
            se[i] += __shfl_xor(se[i], o, 64);
            sey[i] += __shfl_xor(sey[i], o, 64);
            sex[i] += __shfl_xor(sex[i], o, 64);
            emax[i] = fmaxf(emax[i], __shfl_xor(emax[i], o, 64));
        }
    }
    if (l15 == 0) {
#pragma unroll
        for (int i = 0; i < 4; i++) {
            int m = quad * 4 + i;
            float inv_se = 1.0f / se[i];
            float dyv = sey[i] * inv_se, dxv = sex[i] * inv_se, conf = emax[i] * inv_se;
            int px = wid * 16 + m;
            sC[px * 65 + 0] = (unsigned)f2bf(dyv);
            sC[px * 65 + 1] = (unsigned)f2bf(dxv);
            sC[px * 65 + 51] = (unsigned)f2bf(conf);
            float* op = out + (size_t)b * 5 * HW + y * 128 + x0 + m;
            op[2 * HW] = dyv; op[3 * HW] = dxv; op[4 * HW] = conf;
        }
    }
    __syncthreads();
    // packed coalesced writeout: 128 px x 64 ch bf16 = 1024 uint4
#pragma unroll
    for (int i = 0; i < 2; i++) {
        int t2 = i * 512 + tid;
        int px = t2 >> 3, seg = t2 & 7;
        const unsigned* sp = sC + px * 65 + seg * 8;
        uint4 o;
        o.x = sp[0] | (sp[1] << 16);
        o.y = sp[2] | (sp[3] << 16);
        o.z = sp[4] | (sp[5] << 16);
        o.w = sp[6] | (sp[7] << 16);
        unsigned short* dst = xb + ((size_t)(b * WP + y0 + (px >> 4) + 2) * WP + x0 + (px & 15) + 2) * 64 + seg * 8;
        *(uint4*)dst = o;
    }
}

// ---------- 16x8-tile MFMA conv: full-W-slice staging, 2 syncs per ks chunk ----------
template <int KS, int OC, bool GELU>
__global__ __launch_bounds__(512, 4) void conv_tile(const unsigned short* __restrict__ in,
                                                    const unsigned short* __restrict__ wb,
                                                    const float* __restrict__ bias,
                                                    unsigned short* __restrict__ outp) {
    constexpr int ICP = KS * 32;
    constexpr int NF = OC / 16;
    constexpr int ABYTES = 240 * 64;            // 12x20 halo, 32ch chunk = 15360
    constexpr int WROWS = 25 * OC;
    constexpr int WGRAN = WROWS * 4;
    __shared__ char smem[ABYTES + WROWS * 64];
    int tid = threadIdx.x;
    int wv = tid >> 6, lane = tid & 63, l15 = lane & 15, quad = lane >> 4;
    int blk = blockIdx.x;                       // 512 = 4 b x 16 ty x 8 tx
    int b = blk >> 7, rem = blk & 127;
    int ty = rem >> 3, tx = rem & 7;
    int y0 = ty * 8, x0 = tx * 16;

    f32x4 acc[NF];
#pragma unroll
    for (int g = 0; g < NF; g++) acc[g] = (f32x4){0.f, 0.f, 0.f, 0.f};

    for (int ks = 0; ks < KS; ks++) {
        __syncthreads();           // prior chunk's compute done
#pragma unroll
        for (int i = 0; i < 2; i++) {
            int g = i * 512 + tid;
            if (g < 960) {
                int px = g >> 2, sub = g & 3;
                int r = px / 20, c = px - r * 20;
                *(uint4*)(smem + px * 64 + (((sub ^ (px >> 1)) & 3) << 4)) =
                    *(const uint4*)(in + ((size_t)(b * WP + y0 + r) * WP + x0 + c) * ICP + ks * 32 + sub * 8);
            }
        }
#pragma unroll
        for (int i = 0; i < (WGRAN + 511) / 512; i++) {
            int g = i * 512 + tid;
            if (g < WGRAN) {
                int nl = g >> 2, sub = g & 3;
                *(uint4*)(smem + ABYTES + nl * 64 + (((sub ^ (nl >> 1)) & 3) << 4)) =
                    *(const uint4*)(wb + (size_t)nl * ICP + ks * 32 + sub * 8);
            }
        }
        __syncthreads();
#pragma unroll
        for (int ky = 0; ky < 5; ky++) {
#pragma unroll
            for (int kx = 0; kx < 5; kx++) {
                int px = (wv + ky) * 20 + l15 + kx;
                s16x8 a = *(const s16x8*)(smem + px * 64 + (((quad ^ (px >> 1)) & 3) << 4));
#pragma unroll
                for (int g = 0; g < NF; g++) {
                    int row = (ky * 5 + kx) * OC + g * 16 + l15;
                    s16x8 bf = *(const s16x8*)(smem + ABYTES + row * 64 + (((quad ^ (row >> 1)) & 3) << 4));
                    acc[g] = __builtin_amdgcn_mfma_f32_16x16x32_bf16(a, bf, acc[g], 0, 0, 0);
                }
            }
        }
    }
    size_t orow = ((size_t)(b * WP + y0 + wv + 2) * WP + x0 + 2) * OC;
#pragma unroll
    for (int g = 0; g < NF; g++) {
        float bv = bias[g * 16 + l15];
#pragma unroll
        for (int r = 0; r < 4; r++) {
            int m = quad * 4 + r;
            float v = acc[g][r] + bv;
            if (GELU) v = gelu_exact(v);
            outp[orow + (size_t)m * OC + g * 16 + l15] = f2bf(v);
        }
    }
}

// ---------- final conv (32->2, OC padded 16) + residual + sky scaling ----------
__global__ __launch_bounds__(512, 4) void conv_final_tile(const unsigned short* __restrict__ in,
                                                          const unsigned short* __restrict__ wb,
                                                          const float* __restrict__ bias,
                                                          float* __restrict__ out) {
    constexpr int ICP = 32, OC = 16;
    constexpr int ABYTES = 240 * 64;
    constexpr int WROWS = 25 * OC;              // 400
    constexpr int WGRAN = WROWS * 4;            // 1600
    __shared__ char smem[ABYTES + WROWS * 64];  // 40960
    int tid = threadIdx.x;
    int wv = tid >> 6, lane = tid & 63, l15 = lane & 15, quad = lane >> 4;
    int blk = blockIdx.x;
    int b = blk >> 7, rem = blk & 127;
    int ty = rem >> 3, tx = rem & 7;
    int y0 = ty * 8, x0 = tx * 16;

#pragma unroll
    for (int i = 0; i < 2; i++) {
        int g = i * 512 + tid;
        if (g < 960) {
            int px = g >> 2, sub = g & 3;
            int r = px / 20, c = px - r * 20;
            *(uint4*)(smem + px * 64 + (((sub ^ (px >> 1)) & 3) << 4)) =
                *(const uint4*)(in + ((size_t)(b * WP + y0 + r) * WP + x0 + c) * ICP + sub * 8);
        }
    }
#pragma unroll
    for (int i = 0; i < 4; i++) {
        int g = i * 512 + tid;
        if (g < WGRAN) {
            int nl = g >> 2, sub = g & 3;
            *(uint4*)(smem + ABYTES + nl * 64 + (((sub ^ (nl >> 1)) & 3) << 4)) =
                *(const uint4*)(wb + (size_t)nl * ICP + sub * 8);
        }
    }
    __syncthreads();
    f32x4 acc = (f32x4){0.f, 0.f, 0.f, 0.f};
#pragma unroll
    for (int ky = 0; ky < 5; ky++) {
#pragma unroll
        for (int kx = 0; kx < 5; kx++) {
            int px = (wv + ky) * 20 + l15 + kx;
            s16x8 a = *(const s16x8*)(smem + px * 64 + (((quad ^ (px >> 1)) & 3) << 4));
            int row = (ky * 5 + kx) * OC + l15;
            s16x8 bf = *(const s16x8*)(smem + ABYTES + row * 64 + (((quad ^ (row >> 1)) & 3) << 4));
            acc = __builtin_amdgcn_mfma_f32_16x16x32_bf16(a, bf, acc, 0, 0, 0);
        }
    }
    if (l15 < 2) {
        float bv = bias[l15];
#pragma unroll
        for (int r = 0; r < 4; r++) {
            int m = quad * 4 + r;
            size_t p5 = (size_t)b * 5 * HW + (y0 + wv) * Ww + x0 + m;
            float a = acc[r] + bv;
            if (l15 == 0) {
                float dyv = out[p5 + 2 * HW];
                out[p5 + HW] = (dyv + a) * 1.6f;   // ddec
            } else {
                float dxv = out[p5 + 3 * HW];
                out[p5] = (dxv + a) * 1.6f;        // dra
            }
        }
    }
}

extern "C" void kernel_launch(void* const* d_in, const int* in_sizes, int n_in,
                              void* d_out, int out_size, void* d_ws, size_t ws_size,
                              hipStream_t stream) {
    const float* rub = (const float*)d_in[0];
    const float* vis = (const float*)d_in[1];
    const float* w0 = (const float*)d_in[2];
    const float* b0 = (const float*)d_in[3];
    const float* w1 = (const float*)d_in[4];
    const float* b1 = (const float*)d_in[5];
    const float* w2 = (const float*)d_in[6];
    const float* b2 = (const float*)d_in[7];
    const float* log_temp = (const float*)d_in[8];
    float* out = (float*)d_out;

    char* ws = (char*)d_ws;
    size_t off = 0;
    const size_t PADPIX = (size_t)Bb * WP * WP;     // 69,696
    unsigned short* kn = (unsigned short*)(ws + off); off += (size_t)NPIX * Dd * 2;
    unsigned short* qn = (unsigned short*)(ws + off); off += (size_t)NPIX * Dd * 2;
    unsigned short* xbp = (unsigned short*)(ws + off); off += PADPIX * 64 * 2;
    unsigned short* h1p = (unsigned short*)(ws + off); off += PADPIX * 32 * 2;
    unsigned short* h2p = (unsigned short*)(ws + off); off += PADPIX * 32 * 2;
    unsigned short* wb0 = (unsigned short*)(ws + off); off += 51200 * 2;
    unsigned short* wb1 = (unsigned short*)(ws + off); off += 25600 * 2;
    unsigned short* wb2 = (unsigned short*)(ws + off); off += 12800 * 2;

    setup_norm<<<5730, 256, 0, stream>>>(w0, w1, w2, wb0, wb1, wb2,
                                         xbp, h1p, h2p, vis, rub, kn, qn);
    corr_block<<<512, 512, 0, stream>>>(qn, kn, log_temp, xbp, out);
    conv_tile<2, 32, true><<<512, 512, 0, stream>>>(xbp, wb0, b0, h1p);
    conv_tile<1, 32, true><<<512, 512, 0, stream>>>(h1p, wb1, b1, h2p);
    conv_final_tile<<<512, 512, 0, stream>>>(h2p, wb2, b2, out);
}